// Round 6
// baseline (83.208 us; speedup 1.0000x reference)
//
#include <hip/hip_runtime.h>

namespace {
constexpr int NA  = 128;
constexpr int NC2 = NA * (NA - 1) / 2;   // 8128
constexpr int NQ  = NC2 / 4;             // 2032 float4 outputs per batch row
constexpr float SCALE = 627.5095f * 0.529177f / 100.0f;  // AU2KCALMOLA/MAX_NRF

typedef float v4 __attribute__((ext_vector_type(4)));

// LDS swizzle: breaks the stride-4 bank cycle of lane-consecutive j reads.
__device__ __forceinline__ int swz(int j) { return j + (j >> 3); }
}

// R6 = R5 with ONE change: nontemporal stores (global_store_dwordx4 nt),
// bypassing L2 write-allocate. The 66.6 MB output exceeds aggregate L2
// (32 MB); streaming it through L2 write-allocates + evicts every line.
// Everything else (aligned lane-consecutive dwordx4 I/O, swizzled SoA LDS,
// sqrt pair-decode amortized over 4 outputs) identical to R5.
__global__ __launch_bounds__(256) void nrf_kernel(
    const float* __restrict__ coords,
    const float* __restrict__ atoms,
    float* __restrict__ out)
{
    __shared__ float sx[NA + NA / 8], sy[NA + NA / 8], sz[NA + NA / 8];
    const int b   = blockIdx.x;
    const int tid = threadIdx.x;

    // Stage coords[b] (384 contiguous floats) -> swizzled SoA.
    const float* cb = coords + (size_t)b * (NA * 3);
    for (int k = tid; k < NA * 3; k += 256) {
        int atom = k / 3;                 // constant div -> magic mul
        int comp = k - atom * 3;
        float v = cb[k];
        int s = swz(atom);
        if (comp == 0)      sx[s] = v;
        else if (comp == 1) sy[s] = v;
        else                sz[s] = v;
    }
    __syncthreads();

    const v4* a4 = (const v4*)atoms;
    v4*       o4 = (v4*)(out + (size_t)b * NC2);   // NC2*4 % 16 == 0 -> aligned

    for (int q = tid; q < NQ; q += 256) {
        int p = 4 * q;
        v4 av = a4[q];                    // issue early; aligned dwordx4

        // decode p -> (i,j): i = floor((1+sqrt(8p+1))/2), +-1 fixup
        int i = (int)((1.0f + sqrtf((float)(8 * p + 1))) * 0.5f);
        int t = (i * (i - 1)) >> 1;       // tri(i)
        if (t > p)      { --i; t -= i; }  // tri(i-1) = tri(i) - new_i
        if (t + i <= p) { t += i; ++i; }  // tri(i+1) = tri(i) + old_i
        int j = p - t;

        v4 res;
        #pragma unroll
        for (int k = 0; k < 4; ++k) {
            int si = swz(i), sj = swz(j);
            float dx = sx[si] - sx[sj];   // si near-uniform -> broadcast
            float dy = sy[si] - sy[sj];   // sj swizzled -> <=4-way
            float dz = sz[si] - sz[sj];
            float d2 = dx * dx + dy * dy + dz * dz;
            // ref: 1/(sqrt(d2))^2 == 1/d2 within ~2 ulp; v_rcp_f32 is 1 ulp
            res[k] = av[k] * SCALE * __builtin_amdgcn_rcpf(d2);
            ++j; if (j == i) { ++i; j = 0; }   // advance (cndmask, no branch)
        }
        __builtin_nontemporal_store(res, &o4[q]);  // dwordx4 nt: skip L2 alloc
    }
}

extern "C" void kernel_launch(void* const* d_in, const int* in_sizes, int n_in,
                              void* d_out, int out_size, void* d_ws, size_t ws_size,
                              hipStream_t stream)
{
    const float* coords = (const float*)d_in[0];
    const float* atoms  = (const float*)d_in[1];
    float*       out    = (float*)d_out;
    const int batch = in_sizes[0] / (NA * 3);    // 2048
    nrf_kernel<<<batch, 256, 0, stream>>>(coords, atoms, out);
}